// Round 8
// baseline (156.377 us; speedup 1.0000x reference)
//
#include <hip/hip_runtime.h>
#include <math.h>

#define TSEQ 2048
#define BB 8
#define EE 128
#define HH 4
#define UHN 512           // E*H
#define KTOP 22           // int(3*ln(2048))
#define BT (BB*TSEQ)      // 16384
#define APITCH 40         // proj LDS pitch (f16) for K=32 chunks (80B rows)
#define OPITCH 76         // out LDS pitch (f16)

typedef _Float16 f16;
typedef f16 f16x2 __attribute__((ext_vector_type(2)));
typedef f16 f16x4 __attribute__((ext_vector_type(4)));
typedef f16 f16x8 __attribute__((ext_vector_type(8)));
typedef float f32x4 __attribute__((ext_vector_type(4)));

__device__ __forceinline__ float2 cmul(float2 a, float2 b) {
  return make_float2(a.x*b.x - a.y*b.y, a.x*b.y + a.y*b.x);
}
__device__ __forceinline__ float2 cadd(float2 a, float2 b) {
  return make_float2(a.x + b.x, a.y + b.y);
}
__device__ __forceinline__ float2 csub(float2 a, float2 b) {
  return make_float2(a.x - b.x, a.y - b.y);
}

// A/B fragment for mfma_f32_16x16x32_f16: lane holds row/col = lane&15,
// k = 16*(e>>2) + 4*((lane>>4)&3) + (e&3). Load as two b64 at [k, k+16].
__device__ __forceinline__ f16x8 ld_frag(const f16* p) {
  f16x4 lo = *(const f16x4*)(p);
  f16x4 hi = *(const f16x4*)(p + 16);
  return __builtin_shufflevector(lo, hi, 0, 1, 2, 3, 4, 5, 6, 7);
}

// ---------------------------------------------------------------------------
// Stage 0 (prep): one-time f16 hi/lo split + transposes. (unchanged)
// ---------------------------------------------------------------------------
__global__ __launch_bounds__(256)
void prep_kernel(const float* __restrict__ hs,
                 const float* __restrict__ wq, const float* __restrict__ wk,
                 const float* __restrict__ wv, const float* __restrict__ wo,
                 f16* __restrict__ hs_h, f16* __restrict__ hs_l,
                 f16* __restrict__ Wt_h, f16* __restrict__ Wt_l,
                 f16* __restrict__ wo_t)
{
  __shared__ float tile[64][65];
  const int bx = blockIdx.x, tid = threadIdx.x;

  if (bx < 1024) {                       // hs split: 8 elems/thread
    size_t base = ((size_t)bx*256 + tid) * 8;
    float4 a = *(const float4*)&hs[base];
    float4 b = *(const float4*)&hs[base + 4];
    float vf[8] = {a.x,a.y,a.z,a.w, b.x,b.y,b.z,b.w};
    f16 h[8], l[8];
#pragma unroll
    for (int j = 0; j < 8; ++j) { h[j] = (f16)vf[j]; l[j] = (f16)(vf[j] - (float)h[j]); }
    *(f16x8*)&hs_h[base] = (f16x8){h[0],h[1],h[2],h[3],h[4],h[5],h[6],h[7]};
    *(f16x8*)&hs_l[base] = (f16x8){l[0],l[1],l[2],l[3],l[4],l[5],l[6],l[7]};
  } else if (bx < 1072) {                // W transpose+split
    int r = bx - 1024;
    int z = r >> 4, rem = r & 15, kt = rem & 1, uht = rem >> 1;
    const float* W = (z == 0) ? wq : (z == 1) ? wk : wv;
#pragma unroll
    for (int rr = 0; rr < 16; ++rr) {
      int idx = tid + 256*rr;
      int krow = idx >> 6, ucol = idx & 63;
      tile[krow][ucol] = W[(size_t)(kt*64 + krow)*UHN + uht*64 + ucol];
    }
    __syncthreads();
#pragma unroll
    for (int rr = 0; rr < 16; ++rr) {
      int idx = tid + 256*rr;
      int orow = idx >> 6, ocol = idx & 63;     // orow=uh-local, ocol=k-local
      float w = tile[ocol][orow];
      f16 h = (f16)w;
      size_t o = ((size_t)z*UHN + uht*64 + orow)*EE + kt*64 + ocol;
      Wt_h[o] = h;
      Wt_l[o] = (f16)(w - (float)h);
    }
  } else {                               // wo transpose -> f16
    int r = bx - 1072;
    int ft = r & 1, uht = r >> 1;
#pragma unroll
    for (int rr = 0; rr < 16; ++rr) {
      int idx = tid + 256*rr;
      int urow = idx >> 6, fcol = idx & 63;
      tile[urow][fcol] = wo[(size_t)(uht*64 + urow)*EE + ft*64 + fcol];
    }
    __syncthreads();
#pragma unroll
    for (int rr = 0; rr < 16; ++rr) {
      int idx = tid + 256*rr;
      int orow = idx >> 6, ocol = idx & 63;     // orow=f-local, ocol=uh-local
      wo_t[(size_t)(ft*64 + orow)*UHN + uht*64 + ocol] = (f16)tile[ocol][orow];
    }
  }
}

// ---------------------------------------------------------------------------
// Stage 1: q/k/v = hs @ W + b via f16-split MFMA. 40KB LDS, 4 blocks/CU.
// (unchanged)
// ---------------------------------------------------------------------------
__global__ __launch_bounds__(256, 4)
void proj_mfma(const f16* __restrict__ hs_h, const f16* __restrict__ hs_l,
               const f16* __restrict__ Wt_h, const f16* __restrict__ Wt_l,
               const float* __restrict__ bq, const float* __restrict__ bk,
               const float* __restrict__ bv,
               float* __restrict__ q_t, float* __restrict__ k_t, f16* __restrict__ v_t)
{
  __shared__ f16 Ah[128*APITCH];
  __shared__ f16 Al[128*APITCH];
  __shared__ f16 Bh[128*APITCH];
  __shared__ f16 Bl[128*APITCH];

  const int z = blockIdx.z;
  const float* bias = (z == 0) ? bq : (z == 1) ? bk : bv;
  const f16* WH = Wt_h + (size_t)z*UHN*EE;
  const f16* WL = Wt_l + (size_t)z*UHN*EE;

  const int tid  = threadIdx.x;
  const int lane = tid & 63, wid = tid >> 6;
  const int wm = wid >> 1, wn = wid & 1;
  const int ln15 = lane & 15, g = lane >> 4;
  const int uh0 = blockIdx.x * 128;
  const int bt0 = blockIdx.y * 128;

  f32x4 acc[4][4] = {};

  for (int kc = 0; kc < 4; ++kc) {
    const int k0 = kc * 32;
    __syncthreads();
#pragma unroll
    for (int r = 0; r < 2; ++r) {
      int idx = tid + 256*r;                   // 0..511
      int row = idx >> 2, seg = (idx & 3) << 3;
      size_t ga = (size_t)(uh0 + row)*EE + k0 + seg;
      *(f16x8*)&Ah[row*APITCH + seg] = *(const f16x8*)&WH[ga];
      *(f16x8*)&Al[row*APITCH + seg] = *(const f16x8*)&WL[ga];
      size_t gb = (size_t)(bt0 + row)*EE + k0 + seg;
      *(f16x8*)&Bh[row*APITCH + seg] = *(const f16x8*)&hs_h[gb];
      *(f16x8*)&Bl[row*APITCH + seg] = *(const f16x8*)&hs_l[gb];
    }
    __syncthreads();
    const int kb = 4*g;
    f16x8 a_h[4], a_l[4], b_h[4], b_l[4];
#pragma unroll
    for (int mf = 0; mf < 4; ++mf) {
      int off = (wm*64 + mf*16 + ln15)*APITCH + kb;
      a_h[mf] = ld_frag(&Ah[off]);
      a_l[mf] = ld_frag(&Al[off]);
    }
#pragma unroll
    for (int nf = 0; nf < 4; ++nf) {
      int off = (wn*64 + nf*16 + ln15)*APITCH + kb;
      b_h[nf] = ld_frag(&Bh[off]);
      b_l[nf] = ld_frag(&Bl[off]);
    }
#pragma unroll
    for (int mf = 0; mf < 4; ++mf)
#pragma unroll
      for (int nf = 0; nf < 4; ++nf) {
        acc[mf][nf] = __builtin_amdgcn_mfma_f32_16x16x32_f16(a_h[mf], b_h[nf], acc[mf][nf], 0, 0, 0);
        acc[mf][nf] = __builtin_amdgcn_mfma_f32_16x16x32_f16(a_h[mf], b_l[nf], acc[mf][nf], 0, 0, 0);
        acc[mf][nf] = __builtin_amdgcn_mfma_f32_16x16x32_f16(a_l[mf], b_h[nf], acc[mf][nf], 0, 0, 0);
      }
  }

  const int b = bt0 >> 11, tb = bt0 & (TSEQ - 1);
  if (z == 2) {
#pragma unroll
    for (int mf = 0; mf < 4; ++mf) {
      int uhb = uh0 + wm*64 + mf*16 + g*4;
      f32x4 bias4 = *(const f32x4*)&bias[uhb];
#pragma unroll
      for (int r = 0; r < 4; ++r) {
        f16* vrow = v_t + ((size_t)(b*UHN + uhb + r))*TSEQ + tb;
#pragma unroll
        for (int nf = 0; nf < 4; ++nf)
          vrow[wn*64 + nf*16 + ln15] = (f16)(acc[mf][nf][r] + bias4[r]);
      }
    }
  } else {
    float* outp = (z == 0) ? q_t : k_t;
#pragma unroll
    for (int mf = 0; mf < 4; ++mf) {
      int uhb = uh0 + wm*64 + mf*16 + g*4;
      f32x4 bias4 = *(const f32x4*)&bias[uhb];
#pragma unroll
      for (int r = 0; r < 4; ++r) {
        size_t rowbase = ((size_t)(b*UHN + uhb + r))*TSEQ + tb;
#pragma unroll
        for (int nf = 0; nf < 4; ++nf)
          outp[rowbase + wn*64 + nf*16 + ln15] = acc[mf][nf][r] + bias4[r];
      }
    }
  }
}

// ---------------------------------------------------------------------------
// Stage 2+3 (fused): radix-8 FFT correlation + top-22.
// ONE block of 1024 threads per (b,u): 4 groups of 256 threads process the
// 4 heads' forward FFTs IN PARALLEL (own 2112-float2 Z region each), product
// is computed in-place pairwise (p <-> partner, S[q]=conj(S[p]), disjoint
// pairs -> no barrier), h-sum is a cross-group LDS reduce, inverse+topk on
// group 0. ~11 block-wide barriers vs 30. LDS ~70KB -> 2 blocks/CU.
// ---------------------------------------------------------------------------
#define ZPAD(g) ((g) + ((g) >> 5))

template<int SGN>  // a + SGN*i*b
__device__ __forceinline__ float2 addim(float2 a, float2 b) {
  return (SGN < 0) ? make_float2(a.x + b.y, a.y - b.x)
                   : make_float2(a.x - b.y, a.y + b.x);
}
template<int SGN>  // a - SGN*i*b
__device__ __forceinline__ float2 subim(float2 a, float2 b) {
  return (SGN < 0) ? make_float2(a.x - b.y, a.y + b.x)
                   : make_float2(a.x + b.y, a.y - b.x);
}

template<int SGN>
__device__ __forceinline__ void dft8(const float2* u, float2* y) {
  const float r2 = 0.70710678118654752440f;
  float2 a0 = cadd(u[0], u[4]), a1 = cadd(u[1], u[5]);
  float2 a2 = cadd(u[2], u[6]), a3 = cadd(u[3], u[7]);
  float2 b0 = csub(u[0], u[4]), b1 = csub(u[1], u[5]);
  float2 b2 = csub(u[2], u[6]), b3 = csub(u[3], u[7]);
  float2 t1 = (SGN < 0) ? make_float2(r2*(b1.x + b1.y), r2*(b1.y - b1.x))
                        : make_float2(r2*(b1.x - b1.y), r2*(b1.y + b1.x));
  float2 t2 = (SGN < 0) ? make_float2(b2.y, -b2.x) : make_float2(-b2.y, b2.x);
  float2 e  = (SGN < 0) ? make_float2(r2*(b3.x + b3.y), r2*(b3.y - b3.x))
                        : make_float2(r2*(b3.x - b3.y), r2*(b3.y + b3.x));
  float2 t3 = (SGN < 0) ? make_float2(e.y, -e.x) : make_float2(-e.y, e.x);
  {
    float2 c0 = cadd(a0, a2), c1 = csub(a0, a2);
    float2 c2 = cadd(a1, a3), c3 = csub(a1, a3);
    y[0] = cadd(c0, c2); y[4] = csub(c0, c2);
    y[2] = addim<SGN>(c1, c3); y[6] = subim<SGN>(c1, c3);
  }
  {
    float2 c0 = cadd(b0, t2), c1 = csub(b0, t2);
    float2 c2 = cadd(t1, t3), c3 = csub(t1, t3);
    y[1] = cadd(c0, c2); y[5] = csub(c0, c2);
    y[3] = addim<SGN>(c1, c3); y[7] = subim<SGN>(c1, c3);
  }
}

__device__ __forceinline__ void fwd_radix8(float2* Z, float2 w1, int base, int eighth) {
  float2 u[8];
#pragma unroll
  for (int t = 0; t < 8; ++t) u[t] = Z[ZPAD(base + eighth*t)];
  float2 y[8];
  dft8<-1>(u, y);
  Z[ZPAD(base)] = y[0];
  float2 w = w1;
  Z[ZPAD(base + eighth)] = cmul(y[1], w);
#pragma unroll
  for (int s = 2; s < 8; ++s) {
    w = cmul(w, w1);
    Z[ZPAD(base + eighth*s)] = cmul(y[s], w);
  }
}

__device__ __forceinline__ void inv_radix8(float2* Z, float2 w1c, int base, int eighth) {
  float2 u[8];
#pragma unroll
  for (int t = 0; t < 8; ++t) u[t] = Z[ZPAD(base + eighth*t)];
  u[1] = cmul(u[1], w1c);
  float2 w = w1c;
#pragma unroll
  for (int t = 2; t < 8; ++t) {
    w = cmul(w, w1c);
    u[t] = cmul(u[t], w);
  }
  float2 y[8];
  dft8<1>(u, y);
#pragma unroll
  for (int s = 0; s < 8; ++s) Z[ZPAD(base + eighth*s)] = y[s];
}

template<int SGN>
__device__ __forceinline__ void radix4_stage(float2* Z, int base) {
  float2 v0 = Z[ZPAD(base)], v1 = Z[ZPAD(base+1)];
  float2 v2 = Z[ZPAD(base+2)], v3 = Z[ZPAD(base+3)];
  float2 c0 = cadd(v0, v2), c1 = csub(v0, v2);
  float2 c2 = cadd(v1, v3), c3 = csub(v1, v3);
  Z[ZPAD(base)]   = cadd(c0, c2);
  Z[ZPAD(base+1)] = addim<SGN>(c1, c3);
  Z[ZPAD(base+2)] = csub(c0, c2);
  Z[ZPAD(base+3)] = subim<SGN>(c1, c3);
}

__global__ __launch_bounds__(1024)
void fftcorr_topk(const float* __restrict__ q_t, const float* __restrict__ k_t,
                  int* __restrict__ delay, float* __restrict__ wgt)
{
  __shared__ float2 Z[4*2112];     // 67,584 B: one 2112 region per head
  __shared__ float2 twl[292];      // 2,336 B

  const int tid = threadIdx.x;
  const int grp = tid >> 8;        // head h = grp
  const int t8  = tid & 255;
  const int bu  = blockIdx.x;
  float2* Zh = Z + grp*2112;

  if (tid < 292) {
    int idx = tid;
    float ang;
    if (idx < 256)      ang = -6.2831853071795864769f * (float)idx / 2048.0f;
    else if (idx < 288) ang = -6.2831853071795864769f * (float)(idx - 256) / 256.0f;
    else                ang = -6.2831853071795864769f * (float)(idx - 288) / 32.0f;
    float s, c;
    sincosf(ang, &s, &c);
    twl[idx] = make_float2(c, s);
  }
  const float2* tw1 = twl;
  const float2* tw2 = twl + 256;
  const float2* tw3 = twl + 288;
  __syncthreads();

  // ---- forward FFT of z = q + i*k for head grp (all 4 heads in parallel) ----
  {
    const float* qp = q_t + ((size_t)bu*HH + grp)*TSEQ;
    const float* kp = k_t + ((size_t)bu*HH + grp)*TSEQ;
    float2 u[8];
#pragma unroll
    for (int t = 0; t < 8; ++t)
      u[t] = make_float2(qp[t8 + 256*t], kp[t8 + 256*t]);
    float2 y[8];
    dft8<-1>(u, y);
    float2 w1 = tw1[t8];
    Zh[ZPAD(t8)] = y[0];
    float2 w = w1;
    Zh[ZPAD(t8 + 256)] = cmul(y[1], w);
#pragma unroll
    for (int s = 2; s < 8; ++s) {
      w = cmul(w, w1);
      Zh[ZPAD(t8 + 256*s)] = cmul(y[s], w);
    }
  }
  __syncthreads();
  fwd_radix8(Zh, tw2[t8 & 31], ((t8 >> 5) << 8) + (t8 & 31), 32);
  __syncthreads();
  fwd_radix8(Zh, tw3[t8 & 3], ((t8 >> 2) << 5) + (t8 & 3), 4);
  __syncthreads();
  radix4_stage<-1>(Zh, 4*t8);
  radix4_stage<-1>(Zh, 4*(t8 + 256));
  __syncthreads();

  // ---- in-place pairwise unpack-product: S = Q*conj(K), S[q]=conj(S[p]) ----
  // pairs (p, partner) are disjoint; owner = min -> no barrier needed inside
#pragma unroll
  for (int r = 0; r < 8; ++r) {
    int p = t8 + (r << 8);
    int f = ((p >> 8) & 7) | (((p >> 5) & 7) << 3) | (((p >> 2) & 7) << 6) | ((p & 3) << 9);
    int nf = (2048 - f) & 2047;
    int q = ((nf & 7) << 8) | (((nf >> 3) & 7) << 5) | (((nf >> 6) & 7) << 2) | ((nf >> 9) & 3);
    if (p > q) continue;
    float2 A = Zh[ZPAD(p)];
    float2 B = Zh[ZPAD(q)];
    float re = 0.5f  * (B.x*A.y + B.y*A.x);
    float im = 0.25f * ((A.x*A.x + A.y*A.y) - (B.x*B.x + B.y*B.y));
    Zh[ZPAD(p)] = make_float2(re, im);
    if (q != p) Zh[ZPAD(q)] = make_float2(re, -im);
  }
  __syncthreads();

  // ---- cross-head sum into group-0 region: 2 positions per thread ----
#pragma unroll
  for (int e = 0; e < 2; ++e) {
    int zp = ZPAD(2*tid + e);
    float2 s = Z[zp];
    s = cadd(s, Z[2112 + zp]);
    s = cadd(s, Z[2*2112 + zp]);
    s = cadd(s, Z[3*2112 + zp]);
    Z[zp] = s;
  }
  __syncthreads();

  // ---- inverse DIT [4,8,8,8] on Z[0..] (group 0; radix4 uses 512 threads) ----
  if (tid < 512) radix4_stage<1>(Z, 4*tid);
  __syncthreads();
  if (grp == 0) {
    float2 w = tw3[t8 & 3]; w.y = -w.y;
    inv_radix8(Z, w, ((t8 >> 2) << 5) + (t8 & 3), 4);
  }
  __syncthreads();
  if (grp == 0) {
    float2 w = tw2[t8 & 31]; w.y = -w.y;
    inv_radix8(Z, w, ((t8 >> 5) << 8) + (t8 & 31), 32);
  }
  __syncthreads();

  // ---- final inverse stage fused with vbuf store + per-thread local max ----
  float* vbuf = (float*)Z;           // 2048 floats over group-0 region
  float* lmf  = vbuf + 2048;         // 256 per-thread maxima
  int*   lii  = (int*)(vbuf + 2304); // 256 per-thread arg-indices
  {
    float2 u[8];
    if (grp == 0) {
#pragma unroll
      for (int t = 0; t < 8; ++t) u[t] = Z[ZPAD(t8 + 256*t)];
    }
    __syncthreads();                 // all reads done before vbuf overwrite
    if (grp == 0) {
      float2 w1c = tw1[t8]; w1c.y = -w1c.y;
      u[1] = cmul(u[1], w1c);
      float2 w = w1c;
#pragma unroll
      for (int t = 2; t < 8; ++t) {
        w = cmul(w, w1c);
        u[t] = cmul(u[t], w);
      }
      float2 y[8];
      dft8<1>(u, y);
      const float scale = 1.0f / (float)(TSEQ * HH);
      float lb = -3.4e38f; int lbi = t8;
#pragma unroll
      for (int s = 0; s < 8; ++s) {
        float x = y[s].x * scale;
        vbuf[t8 + 256*s] = x;
        if (x > lb) { lb = x; lbi = t8 + 256*s; }  // s ascending -> earliest idx
      }
      lmf[t8] = lb;
      lii[t8] = lbi;
    }
  }
  __syncthreads();

  // ---- top-22: wave 0, wave-synchronous, no barriers ----
  if (tid < 64) {
    const int lane = tid;
    float m0 = 0.f, ssum = 0.f;      // lane 0 only
    for (int it = 0; it < KTOP; ++it) {
      float best = -3.4e38f; int bi = 0x40000000;
#pragma unroll
      for (int e = 0; e < 4; ++e) {
        float x = lmf[4*lane + e];
        int  xi = lii[4*lane + e];
        if (x > best || (x == best && xi < bi)) { best = x; bi = xi; }
      }
#pragma unroll
      for (int off = 32; off > 0; off >>= 1) {
        float ob = __shfl_down(best, off);
        int   oi = __shfl_down(bi, off);
        if (ob > best || (ob == best && oi < bi)) { best = ob; bi = oi; }
      }
      float gb = __shfl(best, 0);
      int   gi = __shfl(bi, 0);
      int   ow = gi & 255;           // owning thread slot
      if (lane == (ow >> 2)) {       // refresh only the winner's slot
        vbuf[gi] = -3.4e38f;
        float nb = -3.4e38f; int ni = ow;
#pragma unroll
        for (int s = 0; s < 8; ++s) {
          float x = vbuf[ow + 256*s];
          if (x > nb) { nb = x; ni = ow + 256*s; }
        }
        lmf[ow] = nb;
        lii[ow] = ni;
      }
      if (lane == 0) {
        if (it == 0) m0 = gb;
        ssum += expf(gb - m0);
        if (it == KTOP - 1) {
          delay[bu] = gi;
          wgt[bu]   = expf(gb - m0) / ssum;
        }
      }
    }
  }
}

// ---------------------------------------------------------------------------
// Stage 4: out = rolled_v @ wo + bo, f16 MFMA; v_t and wo_t are f16. (unchanged)
// ---------------------------------------------------------------------------
__global__ __launch_bounds__(256)
void out_mfma(const f16* __restrict__ v_t, const int* __restrict__ delay,
              const float* __restrict__ wgt, const f16* __restrict__ wo_t,
              const float* __restrict__ bo, float* __restrict__ out)
{
  __shared__ f16 Af[64*OPITCH];
  __shared__ f16 Bf[64*OPITCH];
  __shared__ int   dly[EE];
  __shared__ float wg[EE];

  const int tid  = threadIdx.x;
  const int lane = tid & 63, wid = tid >> 6;
  const int wm = wid >> 1, wn = wid & 1;
  const int ln15 = lane & 15, g = lane >> 4;
  const int t0g = blockIdx.x * 64;
  const int f0  = blockIdx.y * 64;
  const int b = t0g >> 11, t0 = t0g & (TSEQ - 1);

  if (tid < EE) { dly[tid] = delay[b*EE + tid]; wg[tid] = wgt[b*EE + tid]; }

  f32x4 acc[2][2] = {};

  for (int c = 0; c < 8; ++c) {
    const int uh0 = c * 64;
    __syncthreads();   // also covers dly/wg visibility on c==0
#pragma unroll
    for (int r = 0; r < 16; ++r) {
      int idx = tid + 256*r;
      int tl = idx & 63, ul = idx >> 6;
      int u = (uh0 + ul) >> 2;
      float x = (float)v_t[((size_t)(b*UHN + uh0 + ul))*TSEQ + ((t0 + tl + dly[u]) & (TSEQ-1))]
                * wg[u];
      Af[tl*OPITCH + ul] = (f16)x;
    }
#pragma unroll
    for (int r = 0; r < 2; ++r) {
      int idx = tid + 256*r;
      int fl = idx >> 3, seg = (idx & 7) << 3;
      const f16* src = &wo_t[(size_t)(f0 + fl)*UHN + uh0 + seg];
      *(f16x4*)&Bf[fl*OPITCH + seg]     = *(const f16x4*)(src);
      *(f16x4*)&Bf[fl*OPITCH + seg + 4] = *(const f16x4*)(src + 4);
    }
    __syncthreads();
#pragma unroll
    for (int ks = 0; ks < 2; ++ks) {
      const int kb = ks*32 + 4*g;
      f16x8 av[2], bv[2];
#pragma unroll
      for (int mf = 0; mf < 2; ++mf)
        av[mf] = ld_frag(&Af[(wm*32 + mf*16 + ln15)*OPITCH + kb]);
#pragma unroll
      for (int nf = 0; nf < 2; ++nf)
        bv[nf] = ld_frag(&Bf[(wn*32 + nf*16 + ln15)*OPITCH + kb]);
#pragma unroll
      for (int mf = 0; mf < 2; ++mf)
#pragma unroll
        for (int nf = 0; nf < 2; ++nf)
          acc[mf][nf] = __builtin_amdgcn_mfma_f32_16x16x32_f16(av[mf], bv[nf], acc[mf][nf], 0, 0, 0);
    }
  }

#pragma unroll
  for (int mf = 0; mf < 2; ++mf)
#pragma unroll
    for (int r = 0; r < 4; ++r) {
      int bt = t0g + wm*32 + mf*16 + g*4 + r;
#pragma unroll
      for (int nf = 0; nf < 2; ++nf) {
        int f = f0 + wn*32 + nf*16 + ln15;
        out[(size_t)bt*EE + f] = acc[mf][nf][r] + bo[f];
      }
    }
}

// ---------------------------------------------------------------------------
extern "C" void kernel_launch(void* const* d_in, const int* in_sizes, int n_in,
                              void* d_out, int out_size, void* d_ws, size_t ws_size,
                              hipStream_t stream) {
  (void)in_sizes; (void)n_in; (void)out_size; (void)ws_size;
  const float* hs = (const float*)d_in[0];
  const float* wq = (const float*)d_in[1];
  const float* bq = (const float*)d_in[2];
  const float* wk = (const float*)d_in[3];
  const float* bk = (const float*)d_in[4];
  const float* wv = (const float*)d_in[5];
  const float* bv = (const float*)d_in[6];
  const float* wo = (const float*)d_in[7];
  const float* bo = (const float*)d_in[8];
  float* out = (float*)d_out;

  // ws layout (bytes): q_t f32 | k_t f32 | v_t f16 | hs_h | hs_l | Wt_h | Wt_l
  //                    | wo_t | delay | wgt   ~= 93.2 MB
  char* p = (char*)d_ws;
  float* q_t  = (float*)p;  p += (size_t)BB*UHN*TSEQ*4;   // 33.55 MB
  float* k_t  = (float*)p;  p += (size_t)BB*UHN*TSEQ*4;
  f16*   v_t  = (f16*)p;    p += (size_t)BB*UHN*TSEQ*2;   // 16.78 MB
  f16*   hs_h = (f16*)p;    p += (size_t)BT*EE*2;         // 4.19 MB
  f16*   hs_l = (f16*)p;    p += (size_t)BT*EE*2;
  f16*   Wt_h = (f16*)p;    p += (size_t)3*UHN*EE*2;      // 0.39 MB
  f16*   Wt_l = (f16*)p;    p += (size_t)3*UHN*EE*2;
  f16*   wo_t = (f16*)p;    p += (size_t)EE*UHN*2;        // 0.13 MB
  int*   delay = (int*)p;   p += BB*EE*4;
  float* wgt   = (float*)p;

  prep_kernel<<<dim3(1088), 256, 0, stream>>>(hs, wq, wk, wv, wo,
                                              hs_h, hs_l, Wt_h, Wt_l, wo_t);
  proj_mfma<<<dim3(4, 128, 3), 256, 0, stream>>>(hs_h, hs_l, Wt_h, Wt_l,
                                                 bq, bk, bv, q_t, k_t, v_t);
  fftcorr_topk<<<dim3(1024), 1024, 0, stream>>>(q_t, k_t, delay, wgt);
  out_mfma<<<dim3(256, 2), 256, 0, stream>>>(v_t, delay, wgt, wo_t, bo, out);
}

// Round 9
// 135.719 us; speedup vs baseline: 1.1522x; 1.1522x over previous
//
#include <hip/hip_runtime.h>
#include <math.h>

#define TSEQ 2048
#define BB 8
#define EE 128
#define HH 4
#define UHN 512           // E*H
#define KTOP 22           // int(3*ln(2048))
#define BT (BB*TSEQ)      // 16384
#define APITCH 40         // proj LDS pitch (f16) for K=32 chunks (80B rows)
#define OPITCH 76         // out LDS pitch (f16)

typedef _Float16 f16;
typedef f16 f16x2 __attribute__((ext_vector_type(2)));
typedef f16 f16x4 __attribute__((ext_vector_type(4)));
typedef f16 f16x8 __attribute__((ext_vector_type(8)));
typedef float f32x4 __attribute__((ext_vector_type(4)));

__device__ __forceinline__ float2 cmul(float2 a, float2 b) {
  return make_float2(a.x*b.x - a.y*b.y, a.x*b.y + a.y*b.x);
}
__device__ __forceinline__ float2 cadd(float2 a, float2 b) {
  return make_float2(a.x + b.x, a.y + b.y);
}
__device__ __forceinline__ float2 csub(float2 a, float2 b) {
  return make_float2(a.x - b.x, a.y - b.y);
}

// A/B fragment for mfma_f32_16x16x32_f16: lane holds row/col = lane&15,
// k = 16*(e>>2) + 4*((lane>>4)&3) + (e&3). Load as two b64 at [k, k+16].
__device__ __forceinline__ f16x8 ld_frag(const f16* p) {
  f16x4 lo = *(const f16x4*)(p);
  f16x4 hi = *(const f16x4*)(p + 16);
  return __builtin_shufflevector(lo, hi, 0, 1, 2, 3, 4, 5, 6, 7);
}

// ---------------------------------------------------------------------------
// Stage 0 (prep): one-time f16 hi/lo split + transposes. (unchanged)
// ---------------------------------------------------------------------------
__global__ __launch_bounds__(256)
void prep_kernel(const float* __restrict__ hs,
                 const float* __restrict__ wq, const float* __restrict__ wk,
                 const float* __restrict__ wv, const float* __restrict__ wo,
                 f16* __restrict__ hs_h, f16* __restrict__ hs_l,
                 f16* __restrict__ Wt_h, f16* __restrict__ Wt_l,
                 f16* __restrict__ wo_t)
{
  __shared__ float tile[64][65];
  const int bx = blockIdx.x, tid = threadIdx.x;

  if (bx < 1024) {                       // hs split: 8 elems/thread
    size_t base = ((size_t)bx*256 + tid) * 8;
    float4 a = *(const float4*)&hs[base];
    float4 b = *(const float4*)&hs[base + 4];
    float vf[8] = {a.x,a.y,a.z,a.w, b.x,b.y,b.z,b.w};
    f16 h[8], l[8];
#pragma unroll
    for (int j = 0; j < 8; ++j) { h[j] = (f16)vf[j]; l[j] = (f16)(vf[j] - (float)h[j]); }
    *(f16x8*)&hs_h[base] = (f16x8){h[0],h[1],h[2],h[3],h[4],h[5],h[6],h[7]};
    *(f16x8*)&hs_l[base] = (f16x8){l[0],l[1],l[2],l[3],l[4],l[5],l[6],l[7]};
  } else if (bx < 1072) {                // W transpose+split
    int r = bx - 1024;
    int z = r >> 4, rem = r & 15, kt = rem & 1, uht = rem >> 1;
    const float* W = (z == 0) ? wq : (z == 1) ? wk : wv;
#pragma unroll
    for (int rr = 0; rr < 16; ++rr) {
      int idx = tid + 256*rr;
      int krow = idx >> 6, ucol = idx & 63;
      tile[krow][ucol] = W[(size_t)(kt*64 + krow)*UHN + uht*64 + ucol];
    }
    __syncthreads();
#pragma unroll
    for (int rr = 0; rr < 16; ++rr) {
      int idx = tid + 256*rr;
      int orow = idx >> 6, ocol = idx & 63;     // orow=uh-local, ocol=k-local
      float w = tile[ocol][orow];
      f16 h = (f16)w;
      size_t o = ((size_t)z*UHN + uht*64 + orow)*EE + kt*64 + ocol;
      Wt_h[o] = h;
      Wt_l[o] = (f16)(w - (float)h);
    }
  } else {                               // wo transpose -> f16
    int r = bx - 1072;
    int ft = r & 1, uht = r >> 1;
#pragma unroll
    for (int rr = 0; rr < 16; ++rr) {
      int idx = tid + 256*rr;
      int urow = idx >> 6, fcol = idx & 63;
      tile[urow][fcol] = wo[(size_t)(uht*64 + urow)*EE + ft*64 + fcol];
    }
    __syncthreads();
#pragma unroll
    for (int rr = 0; rr < 16; ++rr) {
      int idx = tid + 256*rr;
      int orow = idx >> 6, ocol = idx & 63;     // orow=f-local, ocol=uh-local
      wo_t[(size_t)(ft*64 + orow)*UHN + uht*64 + ocol] = (f16)tile[ocol][orow];
    }
  }
}

// ---------------------------------------------------------------------------
// Stage 1: q/k/v = hs @ W + b via f16-split MFMA. 40KB LDS, 4 blocks/CU.
// (unchanged)
// ---------------------------------------------------------------------------
__global__ __launch_bounds__(256, 4)
void proj_mfma(const f16* __restrict__ hs_h, const f16* __restrict__ hs_l,
               const f16* __restrict__ Wt_h, const f16* __restrict__ Wt_l,
               const float* __restrict__ bq, const float* __restrict__ bk,
               const float* __restrict__ bv,
               float* __restrict__ q_t, float* __restrict__ k_t, f16* __restrict__ v_t)
{
  __shared__ f16 Ah[128*APITCH];
  __shared__ f16 Al[128*APITCH];
  __shared__ f16 Bh[128*APITCH];
  __shared__ f16 Bl[128*APITCH];

  const int z = blockIdx.z;
  const float* bias = (z == 0) ? bq : (z == 1) ? bk : bv;
  const f16* WH = Wt_h + (size_t)z*UHN*EE;
  const f16* WL = Wt_l + (size_t)z*UHN*EE;

  const int tid  = threadIdx.x;
  const int lane = tid & 63, wid = tid >> 6;
  const int wm = wid >> 1, wn = wid & 1;
  const int ln15 = lane & 15, g = lane >> 4;
  const int uh0 = blockIdx.x * 128;
  const int bt0 = blockIdx.y * 128;

  f32x4 acc[4][4] = {};

  for (int kc = 0; kc < 4; ++kc) {
    const int k0 = kc * 32;
    __syncthreads();
#pragma unroll
    for (int r = 0; r < 2; ++r) {
      int idx = tid + 256*r;                   // 0..511
      int row = idx >> 2, seg = (idx & 3) << 3;
      size_t ga = (size_t)(uh0 + row)*EE + k0 + seg;
      *(f16x8*)&Ah[row*APITCH + seg] = *(const f16x8*)&WH[ga];
      *(f16x8*)&Al[row*APITCH + seg] = *(const f16x8*)&WL[ga];
      size_t gb = (size_t)(bt0 + row)*EE + k0 + seg;
      *(f16x8*)&Bh[row*APITCH + seg] = *(const f16x8*)&hs_h[gb];
      *(f16x8*)&Bl[row*APITCH + seg] = *(const f16x8*)&hs_l[gb];
    }
    __syncthreads();
    const int kb = 4*g;
    f16x8 a_h[4], a_l[4], b_h[4], b_l[4];
#pragma unroll
    for (int mf = 0; mf < 4; ++mf) {
      int off = (wm*64 + mf*16 + ln15)*APITCH + kb;
      a_h[mf] = ld_frag(&Ah[off]);
      a_l[mf] = ld_frag(&Al[off]);
    }
#pragma unroll
    for (int nf = 0; nf < 4; ++nf) {
      int off = (wn*64 + nf*16 + ln15)*APITCH + kb;
      b_h[nf] = ld_frag(&Bh[off]);
      b_l[nf] = ld_frag(&Bl[off]);
    }
#pragma unroll
    for (int mf = 0; mf < 4; ++mf)
#pragma unroll
      for (int nf = 0; nf < 4; ++nf) {
        acc[mf][nf] = __builtin_amdgcn_mfma_f32_16x16x32_f16(a_h[mf], b_h[nf], acc[mf][nf], 0, 0, 0);
        acc[mf][nf] = __builtin_amdgcn_mfma_f32_16x16x32_f16(a_h[mf], b_l[nf], acc[mf][nf], 0, 0, 0);
        acc[mf][nf] = __builtin_amdgcn_mfma_f32_16x16x32_f16(a_l[mf], b_h[nf], acc[mf][nf], 0, 0, 0);
      }
  }

  const int b = bt0 >> 11, tb = bt0 & (TSEQ - 1);
  if (z == 2) {
#pragma unroll
    for (int mf = 0; mf < 4; ++mf) {
      int uhb = uh0 + wm*64 + mf*16 + g*4;
      f32x4 bias4 = *(const f32x4*)&bias[uhb];
#pragma unroll
      for (int r = 0; r < 4; ++r) {
        f16* vrow = v_t + ((size_t)(b*UHN + uhb + r))*TSEQ + tb;
#pragma unroll
        for (int nf = 0; nf < 4; ++nf)
          vrow[wn*64 + nf*16 + ln15] = (f16)(acc[mf][nf][r] + bias4[r]);
      }
    }
  } else {
    float* outp = (z == 0) ? q_t : k_t;
#pragma unroll
    for (int mf = 0; mf < 4; ++mf) {
      int uhb = uh0 + wm*64 + mf*16 + g*4;
      f32x4 bias4 = *(const f32x4*)&bias[uhb];
#pragma unroll
      for (int r = 0; r < 4; ++r) {
        size_t rowbase = ((size_t)(b*UHN + uhb + r))*TSEQ + tb;
#pragma unroll
        for (int nf = 0; nf < 4; ++nf)
          outp[rowbase + wn*64 + nf*16 + ln15] = acc[mf][nf][r] + bias4[r];
      }
    }
  }
}

// ---------------------------------------------------------------------------
// Stage 2+3 (fused): radix-8 FFT correlation + top-22.
// ONE block of 512 threads per (b,u): 2 groups of 256 threads, group g runs
// heads {g, g+2} SERIALLY in its own 2112-float2 Z region with S accumulated
// in registers (r5's proven 64-VGPR body); one LDS exchange merges group-1's
// partial into group 0; inverse DIT + wave-sync top-22 as in r7.
// LDS ~36KB -> 4 blocks/CU; grid 1024 -> 4 blocks/CU -> 32 waves/CU.
// ---------------------------------------------------------------------------
#define ZPAD(g) ((g) + ((g) >> 5))

template<int SGN>  // a + SGN*i*b
__device__ __forceinline__ float2 addim(float2 a, float2 b) {
  return (SGN < 0) ? make_float2(a.x + b.y, a.y - b.x)
                   : make_float2(a.x - b.y, a.y + b.x);
}
template<int SGN>  // a - SGN*i*b
__device__ __forceinline__ float2 subim(float2 a, float2 b) {
  return (SGN < 0) ? make_float2(a.x - b.y, a.y + b.x)
                   : make_float2(a.x + b.y, a.y - b.x);
}

template<int SGN>
__device__ __forceinline__ void dft8(const float2* u, float2* y) {
  const float r2 = 0.70710678118654752440f;
  float2 a0 = cadd(u[0], u[4]), a1 = cadd(u[1], u[5]);
  float2 a2 = cadd(u[2], u[6]), a3 = cadd(u[3], u[7]);
  float2 b0 = csub(u[0], u[4]), b1 = csub(u[1], u[5]);
  float2 b2 = csub(u[2], u[6]), b3 = csub(u[3], u[7]);
  float2 t1 = (SGN < 0) ? make_float2(r2*(b1.x + b1.y), r2*(b1.y - b1.x))
                        : make_float2(r2*(b1.x - b1.y), r2*(b1.y + b1.x));
  float2 t2 = (SGN < 0) ? make_float2(b2.y, -b2.x) : make_float2(-b2.y, b2.x);
  float2 e  = (SGN < 0) ? make_float2(r2*(b3.x + b3.y), r2*(b3.y - b3.x))
                        : make_float2(r2*(b3.x - b3.y), r2*(b3.y + b3.x));
  float2 t3 = (SGN < 0) ? make_float2(e.y, -e.x) : make_float2(-e.y, e.x);
  {
    float2 c0 = cadd(a0, a2), c1 = csub(a0, a2);
    float2 c2 = cadd(a1, a3), c3 = csub(a1, a3);
    y[0] = cadd(c0, c2); y[4] = csub(c0, c2);
    y[2] = addim<SGN>(c1, c3); y[6] = subim<SGN>(c1, c3);
  }
  {
    float2 c0 = cadd(b0, t2), c1 = csub(b0, t2);
    float2 c2 = cadd(t1, t3), c3 = csub(t1, t3);
    y[1] = cadd(c0, c2); y[5] = csub(c0, c2);
    y[3] = addim<SGN>(c1, c3); y[7] = subim<SGN>(c1, c3);
  }
}

__device__ __forceinline__ void fwd_radix8(float2* Z, float2 w1, int base, int eighth) {
  float2 u[8];
#pragma unroll
  for (int t = 0; t < 8; ++t) u[t] = Z[ZPAD(base + eighth*t)];
  float2 y[8];
  dft8<-1>(u, y);
  Z[ZPAD(base)] = y[0];
  float2 w = w1;
  Z[ZPAD(base + eighth)] = cmul(y[1], w);
#pragma unroll
  for (int s = 2; s < 8; ++s) {
    w = cmul(w, w1);
    Z[ZPAD(base + eighth*s)] = cmul(y[s], w);
  }
}

__device__ __forceinline__ void inv_radix8(float2* Z, float2 w1c, int base, int eighth) {
  float2 u[8];
#pragma unroll
  for (int t = 0; t < 8; ++t) u[t] = Z[ZPAD(base + eighth*t)];
  u[1] = cmul(u[1], w1c);
  float2 w = w1c;
#pragma unroll
  for (int t = 2; t < 8; ++t) {
    w = cmul(w, w1c);
    u[t] = cmul(u[t], w);
  }
  float2 y[8];
  dft8<1>(u, y);
#pragma unroll
  for (int s = 0; s < 8; ++s) Z[ZPAD(base + eighth*s)] = y[s];
}

template<int SGN>
__device__ __forceinline__ void radix4_stage(float2* Z, int base) {
  float2 v0 = Z[ZPAD(base)], v1 = Z[ZPAD(base+1)];
  float2 v2 = Z[ZPAD(base+2)], v3 = Z[ZPAD(base+3)];
  float2 c0 = cadd(v0, v2), c1 = csub(v0, v2);
  float2 c2 = cadd(v1, v3), c3 = csub(v1, v3);
  Z[ZPAD(base)]   = cadd(c0, c2);
  Z[ZPAD(base+1)] = addim<SGN>(c1, c3);
  Z[ZPAD(base+2)] = csub(c0, c2);
  Z[ZPAD(base+3)] = subim<SGN>(c1, c3);
}

__global__ __launch_bounds__(512, 4)
void fftcorr_topk(const float* __restrict__ q_t, const float* __restrict__ k_t,
                  int* __restrict__ delay, float* __restrict__ wgt)
{
  __shared__ float2 Z[2*2112];     // one 2112 region per thread-group
  __shared__ float2 twl[292];

  const int tid = threadIdx.x;
  const int grp = tid >> 8;        // 0 or 1
  const int t8  = tid & 255;
  const int bu  = blockIdx.x;
  float2* Zh = Z + grp*2112;

  if (tid < 292) {
    int idx = tid;
    float ang;
    if (idx < 256)      ang = -6.2831853071795864769f * (float)idx / 2048.0f;
    else if (idx < 288) ang = -6.2831853071795864769f * (float)(idx - 256) / 256.0f;
    else                ang = -6.2831853071795864769f * (float)(idx - 288) / 32.0f;
    float s, c;
    sincosf(ang, &s, &c);
    twl[idx] = make_float2(c, s);
  }
  const float2* tw1 = twl;
  const float2* tw2 = twl + 256;
  const float2* tw3 = twl + 288;

  int pp[8];
#pragma unroll
  for (int r = 0; r < 8; ++r) {
    int p = t8 + (r << 8);
    int f = ((p >> 8) & 7) | (((p >> 5) & 7) << 3) | (((p >> 2) & 7) << 6) | ((p & 3) << 9);
    int nf = (2048 - f) & 2047;
    pp[r] = ((nf & 7) << 8) | (((nf >> 3) & 7) << 5) | (((nf >> 6) & 7) << 2) | ((nf >> 9) & 3);
  }
  float2 sreg[8] = {};
  __syncthreads();

  // ---- group g: heads {g, g+2} serially; 2 forward FFTs in parallel groups ----
  for (int r2 = 0; r2 < 2; ++r2) {
    const int h = grp + 2*r2;
    const float* qp = q_t + ((size_t)bu*HH + h)*TSEQ;
    const float* kp = k_t + ((size_t)bu*HH + h)*TSEQ;
    if (r2) __syncthreads();         // prior product reads done before overwrite
    {
      float2 u[8];
#pragma unroll
      for (int t = 0; t < 8; ++t)
        u[t] = make_float2(qp[t8 + 256*t], kp[t8 + 256*t]);
      float2 y[8];
      dft8<-1>(u, y);
      float2 w1 = tw1[t8];
      Zh[ZPAD(t8)] = y[0];
      float2 w = w1;
      Zh[ZPAD(t8 + 256)] = cmul(y[1], w);
#pragma unroll
      for (int s = 2; s < 8; ++s) {
        w = cmul(w, w1);
        Zh[ZPAD(t8 + 256*s)] = cmul(y[s], w);
      }
    }
    __syncthreads();
    fwd_radix8(Zh, tw2[t8 & 31], ((t8 >> 5) << 8) + (t8 & 31), 32);
    __syncthreads();
    fwd_radix8(Zh, tw3[t8 & 3], ((t8 >> 2) << 5) + (t8 & 3), 4);
    __syncthreads();
    radix4_stage<-1>(Zh, 4*t8);
    radix4_stage<-1>(Zh, 4*(t8 + 256));
    __syncthreads();
    // S += Q * conj(K) in digit-reversed order, accumulated in registers
#pragma unroll
    for (int r = 0; r < 8; ++r) {
      int p = t8 + (r << 8);
      float2 A  = Zh[ZPAD(p)];
      float2 Zp = Zh[ZPAD(pp[r])];
      sreg[r].x += 0.5f  * (Zp.x*A.y + Zp.y*A.x);
      sreg[r].y += 0.25f * ((A.x*A.x + A.y*A.y) - (Zp.x*Zp.x + Zp.y*Zp.y));
    }
  }
  __syncthreads();                   // all product reads done before Z reuse

  // ---- merge: group 1 deposits its partial S; group 0 sums into Z0 ----
  if (grp == 1) {
#pragma unroll
    for (int r = 0; r < 8; ++r) Zh[ZPAD(t8 + (r << 8))] = sreg[r];
  }
  __syncthreads();
  if (grp == 0) {
#pragma unroll
    for (int r = 0; r < 8; ++r) {
      int zp = ZPAD(t8 + (r << 8));
      Z[zp] = cadd(sreg[r], Z[2112 + zp]);
    }
  }
  __syncthreads();

  // ---- inverse DIT [4,8,8,8] on Z0 (group 0; group 1 idles at barriers) ----
  if (grp == 0) {
    radix4_stage<1>(Z, 4*t8);
    radix4_stage<1>(Z, 4*(t8 + 256));
  }
  __syncthreads();
  if (grp == 0) {
    float2 w = tw3[t8 & 3]; w.y = -w.y;
    inv_radix8(Z, w, ((t8 >> 2) << 5) + (t8 & 3), 4);
  }
  __syncthreads();
  if (grp == 0) {
    float2 w = tw2[t8 & 31]; w.y = -w.y;
    inv_radix8(Z, w, ((t8 >> 5) << 8) + (t8 & 31), 32);
  }
  __syncthreads();

  // ---- final inverse stage fused with vbuf store + per-thread local max ----
  float* vbuf = (float*)Z;           // 2048 floats over group-0 region
  float* lmf  = vbuf + 2048;         // 256 per-thread maxima
  int*   lii  = (int*)(vbuf + 2304); // 256 per-thread arg-indices
  {
    float2 u[8];
    if (grp == 0) {
#pragma unroll
      for (int t = 0; t < 8; ++t) u[t] = Z[ZPAD(t8 + 256*t)];
    }
    __syncthreads();                 // all reads done before vbuf overwrite
    if (grp == 0) {
      float2 w1c = tw1[t8]; w1c.y = -w1c.y;
      u[1] = cmul(u[1], w1c);
      float2 w = w1c;
#pragma unroll
      for (int t = 2; t < 8; ++t) {
        w = cmul(w, w1c);
        u[t] = cmul(u[t], w);
      }
      float2 y[8];
      dft8<1>(u, y);
      const float scale = 1.0f / (float)(TSEQ * HH);
      float lb = -3.4e38f; int lbi = t8;
#pragma unroll
      for (int s = 0; s < 8; ++s) {
        float x = y[s].x * scale;
        vbuf[t8 + 256*s] = x;
        if (x > lb) { lb = x; lbi = t8 + 256*s; }  // s ascending -> earliest idx
      }
      lmf[t8] = lb;
      lii[t8] = lbi;
    }
  }
  __syncthreads();

  // ---- top-22: wave 0, wave-synchronous, no barriers ----
  if (tid < 64) {
    const int lane = tid;
    float m0 = 0.f, ssum = 0.f;      // lane 0 only
    for (int it = 0; it < KTOP; ++it) {
      float best = -3.4e38f; int bi = 0x40000000;
#pragma unroll
      for (int e = 0; e < 4; ++e) {
        float x = lmf[4*lane + e];
        int  xi = lii[4*lane + e];
        if (x > best || (x == best && xi < bi)) { best = x; bi = xi; }
      }
#pragma unroll
      for (int off = 32; off > 0; off >>= 1) {
        float ob = __shfl_down(best, off);
        int   oi = __shfl_down(bi, off);
        if (ob > best || (ob == best && oi < bi)) { best = ob; bi = oi; }
      }
      float gb = __shfl(best, 0);
      int   gi = __shfl(bi, 0);
      int   ow = gi & 255;           // owning thread slot
      if (lane == (ow >> 2)) {       // refresh only the winner's slot
        vbuf[gi] = -3.4e38f;
        float nb = -3.4e38f; int ni = ow;
#pragma unroll
        for (int s = 0; s < 8; ++s) {
          float x = vbuf[ow + 256*s];
          if (x > nb) { nb = x; ni = ow + 256*s; }
        }
        lmf[ow] = nb;
        lii[ow] = ni;
      }
      if (lane == 0) {
        if (it == 0) m0 = gb;
        ssum += expf(gb - m0);
        if (it == KTOP - 1) {
          delay[bu] = gi;
          wgt[bu]   = expf(gb - m0) / ssum;
        }
      }
    }
  }
}

// ---------------------------------------------------------------------------
// Stage 4: out = rolled_v @ wo + bo, f16 MFMA; v_t and wo_t are f16. (unchanged)
// ---------------------------------------------------------------------------
__global__ __launch_bounds__(256)
void out_mfma(const f16* __restrict__ v_t, const int* __restrict__ delay,
              const float* __restrict__ wgt, const f16* __restrict__ wo_t,
              const float* __restrict__ bo, float* __restrict__ out)
{
  __shared__ f16 Af[64*OPITCH];
  __shared__ f16 Bf[64*OPITCH];
  __shared__ int   dly[EE];
  __shared__ float wg[EE];

  const int tid  = threadIdx.x;
  const int lane = tid & 63, wid = tid >> 6;
  const int wm = wid >> 1, wn = wid & 1;
  const int ln15 = lane & 15, g = lane >> 4;
  const int t0g = blockIdx.x * 64;
  const int f0  = blockIdx.y * 64;
  const int b = t0g >> 11, t0 = t0g & (TSEQ - 1);

  if (tid < EE) { dly[tid] = delay[b*EE + tid]; wg[tid] = wgt[b*EE + tid]; }

  f32x4 acc[2][2] = {};

  for (int c = 0; c < 8; ++c) {
    const int uh0 = c * 64;
    __syncthreads();   // also covers dly/wg visibility on c==0
#pragma unroll
    for (int r = 0; r < 16; ++r) {
      int idx = tid + 256*r;
      int tl = idx & 63, ul = idx >> 6;
      int u = (uh0 + ul) >> 2;
      float x = (float)v_t[((size_t)(b*UHN + uh0 + ul))*TSEQ + ((t0 + tl + dly[u]) & (TSEQ-1))]
                * wg[u];
      Af[tl*OPITCH + ul] = (f16)x;
    }
#pragma unroll
    for (int r = 0; r < 2; ++r) {
      int idx = tid + 256*r;
      int fl = idx >> 3, seg = (idx & 7) << 3;
      const f16* src = &wo_t[(size_t)(f0 + fl)*UHN + uh0 + seg];
      *(f16x4*)&Bf[fl*OPITCH + seg]     = *(const f16x4*)(src);
      *(f16x4*)&Bf[fl*OPITCH + seg + 4] = *(const f16x4*)(src + 4);
    }
    __syncthreads();
#pragma unroll
    for (int ks = 0; ks < 2; ++ks) {
      const int kb = ks*32 + 4*g;
      f16x8 av[2], bv[2];
#pragma unroll
      for (int mf = 0; mf < 2; ++mf)
        av[mf] = ld_frag(&Af[(wm*32 + mf*16 + ln15)*OPITCH + kb]);
#pragma unroll
      for (int nf = 0; nf < 2; ++nf)
        bv[nf] = ld_frag(&Bf[(wn*32 + nf*16 + ln15)*OPITCH + kb]);
#pragma unroll
      for (int mf = 0; mf < 2; ++mf)
#pragma unroll
        for (int nf = 0; nf < 2; ++nf)
          acc[mf][nf] = __builtin_amdgcn_mfma_f32_16x16x32_f16(av[mf], bv[nf], acc[mf][nf], 0, 0, 0);
    }
  }

#pragma unroll
  for (int mf = 0; mf < 2; ++mf)
#pragma unroll
    for (int r = 0; r < 4; ++r) {
      int bt = t0g + wm*32 + mf*16 + g*4 + r;
#pragma unroll
      for (int nf = 0; nf < 2; ++nf) {
        int f = f0 + wn*32 + nf*16 + ln15;
        out[(size_t)bt*EE + f] = acc[mf][nf][r] + bo[f];
      }
    }
}

// ---------------------------------------------------------------------------
extern "C" void kernel_launch(void* const* d_in, const int* in_sizes, int n_in,
                              void* d_out, int out_size, void* d_ws, size_t ws_size,
                              hipStream_t stream) {
  (void)in_sizes; (void)n_in; (void)out_size; (void)ws_size;
  const float* hs = (const float*)d_in[0];
  const float* wq = (const float*)d_in[1];
  const float* bq = (const float*)d_in[2];
  const float* wk = (const float*)d_in[3];
  const float* bk = (const float*)d_in[4];
  const float* wv = (const float*)d_in[5];
  const float* bv = (const float*)d_in[6];
  const float* wo = (const float*)d_in[7];
  const float* bo = (const float*)d_in[8];
  float* out = (float*)d_out;

  // ws layout (bytes): q_t f32 | k_t f32 | v_t f16 | hs_h | hs_l | Wt_h | Wt_l
  //                    | wo_t | delay | wgt   ~= 93.2 MB
  char* p = (char*)d_ws;
  float* q_t  = (float*)p;  p += (size_t)BB*UHN*TSEQ*4;   // 33.55 MB
  float* k_t  = (float*)p;  p += (size_t)BB*UHN*TSEQ*4;
  f16*   v_t  = (f16*)p;    p += (size_t)BB*UHN*TSEQ*2;   // 16.78 MB
  f16*   hs_h = (f16*)p;    p += (size_t)BT*EE*2;         // 4.19 MB
  f16*   hs_l = (f16*)p;    p += (size_t)BT*EE*2;
  f16*   Wt_h = (f16*)p;    p += (size_t)3*UHN*EE*2;      // 0.39 MB
  f16*   Wt_l = (f16*)p;    p += (size_t)3*UHN*EE*2;
  f16*   wo_t = (f16*)p;    p += (size_t)EE*UHN*2;        // 0.13 MB
  int*   delay = (int*)p;   p += BB*EE*4;
  float* wgt   = (float*)p;

  prep_kernel<<<dim3(1088), 256, 0, stream>>>(hs, wq, wk, wv, wo,
                                              hs_h, hs_l, Wt_h, Wt_l, wo_t);
  proj_mfma<<<dim3(4, 128, 3), 256, 0, stream>>>(hs_h, hs_l, Wt_h, Wt_l,
                                                 bq, bk, bv, q_t, k_t, v_t);
  fftcorr_topk<<<dim3(1024), 512, 0, stream>>>(q_t, k_t, delay, wgt);
  out_mfma<<<dim3(256, 2), 256, 0, stream>>>(v_t, delay, wgt, wo_t, bo, out);
}

// Round 10
// 115.724 us; speedup vs baseline: 1.3513x; 1.1728x over previous
//
#include <hip/hip_runtime.h>
#include <math.h>

#define TSEQ 2048
#define BB 8
#define EE 128
#define HH 4
#define UHN 512           // E*H
#define KTOP 22           // int(3*ln(2048))
#define BT (BB*TSEQ)      // 16384
#define APITCH 40         // proj LDS pitch (f16) for K=32 chunks (80B rows)
#define OPITCH 76         // out LDS pitch (f16)

typedef _Float16 f16;
typedef f16 f16x2 __attribute__((ext_vector_type(2)));
typedef f16 f16x4 __attribute__((ext_vector_type(4)));
typedef f16 f16x8 __attribute__((ext_vector_type(8)));
typedef float f32x4 __attribute__((ext_vector_type(4)));
typedef float cpx  __attribute__((ext_vector_type(2)));   // complex: {re, im}

// packed complex helpers (vector ops -> v_pk_add/mul/fma_f32 on gfx950)
__device__ __forceinline__ cpx cmul(cpx a, cpx b) {
  cpx r = (cpx){a.x, a.x} * b;
  r += (cpx){-a.y, a.y} * (cpx){b.y, b.x};
  return r;
}
template<int SGN>  // SGN * i * b
__device__ __forceinline__ cpx muli(cpx b) {
  return (SGN < 0) ? (cpx){b.y, -b.x} : (cpx){-b.y, b.x};
}

// A/B fragment for mfma_f32_16x16x32_f16: lane holds row/col = lane&15,
// k = 16*(e>>2) + 4*((lane>>4)&3) + (e&3). Load as two b64 at [k, k+16].
__device__ __forceinline__ f16x8 ld_frag(const f16* p) {
  f16x4 lo = *(const f16x4*)(p);
  f16x4 hi = *(const f16x4*)(p + 16);
  return __builtin_shufflevector(lo, hi, 0, 1, 2, 3, 4, 5, 6, 7);
}

// ---------------------------------------------------------------------------
// Stage 0 (prep): one-time f16 hi/lo split + transposes.
// ---------------------------------------------------------------------------
__global__ __launch_bounds__(256)
void prep_kernel(const float* __restrict__ hs,
                 const float* __restrict__ wq, const float* __restrict__ wk,
                 const float* __restrict__ wv, const float* __restrict__ wo,
                 f16* __restrict__ hs_h, f16* __restrict__ hs_l,
                 f16* __restrict__ Wt_h, f16* __restrict__ Wt_l,
                 f16* __restrict__ wo_t)
{
  __shared__ float tile[64][65];
  const int bx = blockIdx.x, tid = threadIdx.x;

  if (bx < 1024) {                       // hs split: 8 elems/thread
    size_t base = ((size_t)bx*256 + tid) * 8;
    float4 a = *(const float4*)&hs[base];
    float4 b = *(const float4*)&hs[base + 4];
    float vf[8] = {a.x,a.y,a.z,a.w, b.x,b.y,b.z,b.w};
    f16 h[8], l[8];
#pragma unroll
    for (int j = 0; j < 8; ++j) { h[j] = (f16)vf[j]; l[j] = (f16)(vf[j] - (float)h[j]); }
    *(f16x8*)&hs_h[base] = (f16x8){h[0],h[1],h[2],h[3],h[4],h[5],h[6],h[7]};
    *(f16x8*)&hs_l[base] = (f16x8){l[0],l[1],l[2],l[3],l[4],l[5],l[6],l[7]};
  } else if (bx < 1072) {                // W transpose+split
    int r = bx - 1024;
    int z = r >> 4, rem = r & 15, kt = rem & 1, uht = rem >> 1;
    const float* W = (z == 0) ? wq : (z == 1) ? wk : wv;
#pragma unroll
    for (int rr = 0; rr < 16; ++rr) {
      int idx = tid + 256*rr;
      int krow = idx >> 6, ucol = idx & 63;
      tile[krow][ucol] = W[(size_t)(kt*64 + krow)*UHN + uht*64 + ucol];
    }
    __syncthreads();
#pragma unroll
    for (int rr = 0; rr < 16; ++rr) {
      int idx = tid + 256*rr;
      int orow = idx >> 6, ocol = idx & 63;     // orow=uh-local, ocol=k-local
      float w = tile[ocol][orow];
      f16 h = (f16)w;
      size_t o = ((size_t)z*UHN + uht*64 + orow)*EE + kt*64 + ocol;
      Wt_h[o] = h;
      Wt_l[o] = (f16)(w - (float)h);
    }
  } else {                               // wo transpose -> f16
    int r = bx - 1072;
    int ft = r & 1, uht = r >> 1;
#pragma unroll
    for (int rr = 0; rr < 16; ++rr) {
      int idx = tid + 256*rr;
      int urow = idx >> 6, fcol = idx & 63;
      tile[urow][fcol] = wo[(size_t)(uht*64 + urow)*EE + ft*64 + fcol];
    }
    __syncthreads();
#pragma unroll
    for (int rr = 0; rr < 16; ++rr) {
      int idx = tid + 256*rr;
      int orow = idx >> 6, ocol = idx & 63;     // orow=f-local, ocol=uh-local
      wo_t[(size_t)(ft*64 + orow)*UHN + uht*64 + ocol] = (f16)tile[ocol][orow];
    }
  }
}

// ---------------------------------------------------------------------------
// Stage 1: q/k/v = hs @ W + b via f16-split MFMA. 40KB LDS, (256,3) — the
// round-5-build config (the (256,4) variant cost ~13us across the pipeline).
// ---------------------------------------------------------------------------
__global__ __launch_bounds__(256, 3)
void proj_mfma(const f16* __restrict__ hs_h, const f16* __restrict__ hs_l,
               const f16* __restrict__ Wt_h, const f16* __restrict__ Wt_l,
               const float* __restrict__ bq, const float* __restrict__ bk,
               const float* __restrict__ bv,
               float* __restrict__ q_t, float* __restrict__ k_t, f16* __restrict__ v_t)
{
  __shared__ f16 Ah[128*APITCH];
  __shared__ f16 Al[128*APITCH];
  __shared__ f16 Bh[128*APITCH];
  __shared__ f16 Bl[128*APITCH];

  const int z = blockIdx.z;
  const float* bias = (z == 0) ? bq : (z == 1) ? bk : bv;
  const f16* WH = Wt_h + (size_t)z*UHN*EE;
  const f16* WL = Wt_l + (size_t)z*UHN*EE;

  const int tid  = threadIdx.x;
  const int lane = tid & 63, wid = tid >> 6;
  const int wm = wid >> 1, wn = wid & 1;
  const int ln15 = lane & 15, g = lane >> 4;
  const int uh0 = blockIdx.x * 128;
  const int bt0 = blockIdx.y * 128;

  f32x4 acc[4][4] = {};

  for (int kc = 0; kc < 4; ++kc) {
    const int k0 = kc * 32;
    __syncthreads();
#pragma unroll
    for (int r = 0; r < 2; ++r) {
      int idx = tid + 256*r;                   // 0..511
      int row = idx >> 2, seg = (idx & 3) << 3;
      size_t ga = (size_t)(uh0 + row)*EE + k0 + seg;
      *(f16x8*)&Ah[row*APITCH + seg] = *(const f16x8*)&WH[ga];
      *(f16x8*)&Al[row*APITCH + seg] = *(const f16x8*)&WL[ga];
      size_t gb = (size_t)(bt0 + row)*EE + k0 + seg;
      *(f16x8*)&Bh[row*APITCH + seg] = *(const f16x8*)&hs_h[gb];
      *(f16x8*)&Bl[row*APITCH + seg] = *(const f16x8*)&hs_l[gb];
    }
    __syncthreads();
    const int kb = 4*g;
    f16x8 a_h[4], a_l[4], b_h[4], b_l[4];
#pragma unroll
    for (int mf = 0; mf < 4; ++mf) {
      int off = (wm*64 + mf*16 + ln15)*APITCH + kb;
      a_h[mf] = ld_frag(&Ah[off]);
      a_l[mf] = ld_frag(&Al[off]);
    }
#pragma unroll
    for (int nf = 0; nf < 4; ++nf) {
      int off = (wn*64 + nf*16 + ln15)*APITCH + kb;
      b_h[nf] = ld_frag(&Bh[off]);
      b_l[nf] = ld_frag(&Bl[off]);
    }
#pragma unroll
    for (int mf = 0; mf < 4; ++mf)
#pragma unroll
      for (int nf = 0; nf < 4; ++nf) {
        acc[mf][nf] = __builtin_amdgcn_mfma_f32_16x16x32_f16(a_h[mf], b_h[nf], acc[mf][nf], 0, 0, 0);
        acc[mf][nf] = __builtin_amdgcn_mfma_f32_16x16x32_f16(a_h[mf], b_l[nf], acc[mf][nf], 0, 0, 0);
        acc[mf][nf] = __builtin_amdgcn_mfma_f32_16x16x32_f16(a_l[mf], b_h[nf], acc[mf][nf], 0, 0, 0);
      }
  }

  const int b = bt0 >> 11, tb = bt0 & (TSEQ - 1);
  if (z == 2) {
#pragma unroll
    for (int mf = 0; mf < 4; ++mf) {
      int uhb = uh0 + wm*64 + mf*16 + g*4;
      f32x4 bias4 = *(const f32x4*)&bias[uhb];
#pragma unroll
      for (int r = 0; r < 4; ++r) {
        f16* vrow = v_t + ((size_t)(b*UHN + uhb + r))*TSEQ + tb;
#pragma unroll
        for (int nf = 0; nf < 4; ++nf)
          vrow[wn*64 + nf*16 + ln15] = (f16)(acc[mf][nf][r] + bias4[r]);
      }
    }
  } else {
    float* outp = (z == 0) ? q_t : k_t;
#pragma unroll
    for (int mf = 0; mf < 4; ++mf) {
      int uhb = uh0 + wm*64 + mf*16 + g*4;
      f32x4 bias4 = *(const f32x4*)&bias[uhb];
#pragma unroll
      for (int r = 0; r < 4; ++r) {
        size_t rowbase = ((size_t)(b*UHN + uhb + r))*TSEQ + tb;
#pragma unroll
        for (int nf = 0; nf < 4; ++nf)
          outp[rowbase + wn*64 + nf*16 + ln15] = acc[mf][nf][r] + bias4[r];
      }
    }
  }
}

// ---------------------------------------------------------------------------
// Stage 2+3 (fused): radix-8 FFT correlation + top-22, 256 threads / (b,u)
// (the best-measured config), with PACKED complex math (v_pk_*_f32) and
// balanced-tree twiddle powers.
// ---------------------------------------------------------------------------
#define ZPAD(g) ((g) + ((g) >> 5))

template<int SGN>
__device__ __forceinline__ void dft8(const cpx* u, cpx* y) {
  const float r2 = 0.70710678118654752440f;
  cpx a0 = u[0] + u[4], a1 = u[1] + u[5];
  cpx a2 = u[2] + u[6], a3 = u[3] + u[7];
  cpx b0 = u[0] - u[4], b1 = u[1] - u[5];
  cpx b2 = u[2] - u[6], b3 = u[3] - u[7];
  cpx t1 = (b1 + muli<SGN>(b1)) * r2;     // b1 * (1 + SGN i)/sqrt2
  cpx t2 = muli<SGN>(b2);                 // b2 * SGN i
  cpx e  = (b3 + muli<SGN>(b3)) * r2;
  cpx t3 = muli<SGN>(e);
  {
    cpx c0 = a0 + a2, c1 = a0 - a2;
    cpx c2 = a1 + a3, c3 = a1 - a3;
    y[0] = c0 + c2; y[4] = c0 - c2;
    y[2] = c1 + muli<SGN>(c3); y[6] = c1 - muli<SGN>(c3);
  }
  {
    cpx c0 = b0 + t2, c1 = b0 - t2;
    cpx c2 = t1 + t3, c3 = t1 - t3;
    y[1] = c0 + c2; y[5] = c0 - c2;
    y[3] = c1 + muli<SGN>(c3); y[7] = c1 - muli<SGN>(c3);
  }
}

// balanced-tree powers w^2..w^7 (dep depth 3 instead of 6)
__device__ __forceinline__ void wpow_tree(cpx w1, cpx* W) {
  W[0] = w1;
  cpx w2 = cmul(w1, w1);
  cpx w4 = cmul(w2, w2);
  W[1] = w2;
  W[2] = cmul(w2, w1);
  W[3] = w4;
  W[4] = cmul(w4, w1);
  W[5] = cmul(w4, w2);
  W[6] = cmul(w4, W[2]);
}

__device__ __forceinline__ void fwd_radix8(cpx* Z, cpx w1, int base, int eighth) {
  cpx u[8];
#pragma unroll
  for (int t = 0; t < 8; ++t) u[t] = Z[ZPAD(base + eighth*t)];
  cpx y[8];
  dft8<-1>(u, y);
  cpx W[7];
  wpow_tree(w1, W);
  Z[ZPAD(base)] = y[0];
#pragma unroll
  for (int s = 1; s < 8; ++s)
    Z[ZPAD(base + eighth*s)] = cmul(y[s], W[s-1]);
}

__device__ __forceinline__ void inv_radix8(cpx* Z, cpx w1c, int base, int eighth) {
  cpx u[8];
#pragma unroll
  for (int t = 0; t < 8; ++t) u[t] = Z[ZPAD(base + eighth*t)];
  cpx W[7];
  wpow_tree(w1c, W);
#pragma unroll
  for (int t = 1; t < 8; ++t) u[t] = cmul(u[t], W[t-1]);
  cpx y[8];
  dft8<1>(u, y);
#pragma unroll
  for (int s = 0; s < 8; ++s) Z[ZPAD(base + eighth*s)] = y[s];
}

template<int SGN>
__device__ __forceinline__ void radix4_stage(cpx* Z, int base) {
  cpx v0 = Z[ZPAD(base)], v1 = Z[ZPAD(base+1)];
  cpx v2 = Z[ZPAD(base+2)], v3 = Z[ZPAD(base+3)];
  cpx c0 = v0 + v2, c1 = v0 - v2;
  cpx c2 = v1 + v3, c3 = v1 - v3;
  Z[ZPAD(base)]   = c0 + c2;
  Z[ZPAD(base+1)] = c1 + muli<SGN>(c3);
  Z[ZPAD(base+2)] = c0 - c2;
  Z[ZPAD(base+3)] = c1 - muli<SGN>(c3);
}

__global__ __launch_bounds__(256)
void fftcorr_topk(const float* __restrict__ q_t, const float* __restrict__ k_t,
                  int* __restrict__ delay, float* __restrict__ wgt)
{
  __shared__ cpx Z[2112];
  __shared__ cpx twl[292];    // tw1[256]: W_2048^j | tw2[32]: W_256^j | tw3[4]: W_32^j

  const int tid = threadIdx.x;
  const int bu  = blockIdx.x;

  for (int idx = tid; idx < 292; idx += 256) {
    float ang;
    if (idx < 256)      ang = -6.2831853071795864769f * (float)idx / 2048.0f;
    else if (idx < 288) ang = -6.2831853071795864769f * (float)(idx - 256) / 256.0f;
    else                ang = -6.2831853071795864769f * (float)(idx - 288) / 32.0f;
    float s, c;
    sincosf(ang, &s, &c);
    twl[idx] = (cpx){c, s};
  }
  const cpx* tw1 = twl;
  const cpx* tw2 = twl + 256;
  const cpx* tw3 = twl + 288;

  int pp[8];
#pragma unroll
  for (int r = 0; r < 8; ++r) {
    int p = tid + (r << 8);
    int f = ((p >> 8) & 7) | (((p >> 5) & 7) << 3) | (((p >> 2) & 7) << 6) | ((p & 3) << 9);
    int nf = (2048 - f) & 2047;
    pp[r] = ((nf & 7) << 8) | (((nf >> 3) & 7) << 5) | (((nf >> 6) & 7) << 2) | ((nf >> 9) & 3);
  }
  cpx sreg[8] = {};
  __syncthreads();

  for (int h = 0; h < HH; ++h) {
    const float* qp = q_t + ((size_t)bu*HH + h)*TSEQ;
    const float* kp = k_t + ((size_t)bu*HH + h)*TSEQ;
    if (h) __syncthreads();          // prior product reads done before overwrite
    {
      cpx u[8];
#pragma unroll
      for (int t = 0; t < 8; ++t)
        u[t] = (cpx){qp[tid + 256*t], kp[tid + 256*t]};
      cpx y[8];
      dft8<-1>(u, y);
      cpx W[7];
      wpow_tree(tw1[tid], W);
      Z[ZPAD(tid)] = y[0];
#pragma unroll
      for (int s = 1; s < 8; ++s)
        Z[ZPAD(tid + 256*s)] = cmul(y[s], W[s-1]);
    }
    __syncthreads();
    fwd_radix8(Z, tw2[tid & 31], ((tid >> 5) << 8) + (tid & 31), 32);
    __syncthreads();
    fwd_radix8(Z, tw3[tid & 3], ((tid >> 2) << 5) + (tid & 3), 4);
    __syncthreads();
    radix4_stage<-1>(Z, 4*tid);
    radix4_stage<-1>(Z, 4*(tid + 256));
    __syncthreads();
    // S += Q * conj(K) in digit-reversed order, accumulated in registers
#pragma unroll
    for (int r = 0; r < 8; ++r) {
      int p = tid + (r << 8);
      cpx A  = Z[ZPAD(p)];
      cpx Zp = Z[ZPAD(pp[r])];
      sreg[r].x += 0.5f  * (Zp.x*A.y + Zp.y*A.x);
      sreg[r].y += 0.25f * ((A.x*A.x + A.y*A.y) - (Zp.x*Zp.x + Zp.y*Zp.y));
    }
  }
  __syncthreads();

  // inverse DIT [4,8,8,8]
#pragma unroll
  for (int r = 0; r < 8; ++r) Z[ZPAD(tid + (r << 8))] = sreg[r];
  __syncthreads();
  radix4_stage<1>(Z, 4*tid);
  radix4_stage<1>(Z, 4*(tid + 256));
  __syncthreads();
  { cpx w = tw3[tid & 3]; w.y = -w.y;
    inv_radix8(Z, w, ((tid >> 2) << 5) + (tid & 3), 4); }
  __syncthreads();
  { cpx w = tw2[tid & 31]; w.y = -w.y;
    inv_radix8(Z, w, ((tid >> 5) << 8) + (tid & 31), 32); }
  __syncthreads();

  // final inverse stage fused with vbuf store + per-thread local max (from regs)
  float* vbuf = (float*)Z;           // 2048 floats (Z region dead after reads)
  float* lmf  = vbuf + 2048;         // 256 per-thread maxima
  int*   lii  = (int*)(vbuf + 2304); // 256 per-thread arg-indices
  {
    cpx u[8];
#pragma unroll
    for (int t = 0; t < 8; ++t) u[t] = Z[ZPAD(tid + 256*t)];
    __syncthreads();               // all reads of Z done before vbuf overwrite
    cpx w1c = tw1[tid]; w1c.y = -w1c.y;
    cpx W[7];
    wpow_tree(w1c, W);
#pragma unroll
    for (int t = 1; t < 8; ++t) u[t] = cmul(u[t], W[t-1]);
    cpx y[8];
    dft8<1>(u, y);
    const float scale = 1.0f / (float)(TSEQ * HH);
    float lb = -3.4e38f; int lbi = tid;
#pragma unroll
    for (int s = 0; s < 8; ++s) {
      float x = y[s].x * scale;
      vbuf[tid + 256*s] = x;
      if (x > lb) { lb = x; lbi = tid + 256*s; }   // s ascending -> earliest idx
    }
    lmf[tid] = lb;
    lii[tid] = lbi;
  }
  __syncthreads();

  // top-22: first wave, wave-synchronous, no barriers.
  if (tid < 64) {
    const int lane = tid;
    float m0 = 0.f, ssum = 0.f;    // lane 0 only
    for (int it = 0; it < KTOP; ++it) {
      float best = -3.4e38f; int bi = 0x40000000;
#pragma unroll
      for (int e = 0; e < 4; ++e) {
        float x = lmf[4*lane + e];
        int  xi = lii[4*lane + e];
        if (x > best || (x == best && xi < bi)) { best = x; bi = xi; }
      }
#pragma unroll
      for (int off = 32; off > 0; off >>= 1) {
        float ob = __shfl_down(best, off);
        int   oi = __shfl_down(bi, off);
        if (ob > best || (ob == best && oi < bi)) { best = ob; bi = oi; }
      }
      float gb = __shfl(best, 0);
      int   gi = __shfl(bi, 0);
      int   ow = gi & 255;           // owning thread slot
      if (lane == (ow >> 2)) {       // refresh only the winner's slot
        vbuf[gi] = -3.4e38f;
        float nb = -3.4e38f; int ni = ow;
#pragma unroll
        for (int s = 0; s < 8; ++s) {
          float x = vbuf[ow + 256*s];
          if (x > nb) { nb = x; ni = ow + 256*s; }
        }
        lmf[ow] = nb;
        lii[ow] = ni;
      }
      if (lane == 0) {
        if (it == 0) m0 = gb;
        ssum += expf(gb - m0);
        if (it == KTOP - 1) {
          delay[bu] = gi;
          wgt[bu]   = expf(gb - m0) / ssum;
        }
      }
    }
  }
}

// ---------------------------------------------------------------------------
// Stage 4: out = rolled_v @ wo + bo, f16 MFMA; v_t and wo_t are f16.
// ---------------------------------------------------------------------------
__global__ __launch_bounds__(256)
void out_mfma(const f16* __restrict__ v_t, const int* __restrict__ delay,
              const float* __restrict__ wgt, const f16* __restrict__ wo_t,
              const float* __restrict__ bo, float* __restrict__ out)
{
  __shared__ f16 Af[64*OPITCH];
  __shared__ f16 Bf[64*OPITCH];
  __shared__ int   dly[EE];
  __shared__ float wg[EE];

  const int tid  = threadIdx.x;
  const int lane = tid & 63, wid = tid >> 6;
  const int wm = wid >> 1, wn = wid & 1;
  const int ln15 = lane & 15, g = lane >> 4;
  const int t0g = blockIdx.x * 64;
  const int f0  = blockIdx.y * 64;
  const int b = t0g >> 11, t0 = t0g & (TSEQ - 1);

  if (tid < EE) { dly[tid] = delay[b*EE + tid]; wg[tid] = wgt[b*EE + tid]; }

  f32x4 acc[2][2] = {};

  for (int c = 0; c < 8; ++c) {
    const int uh0 = c * 64;
    __syncthreads();   // also covers dly/wg visibility on c==0
#pragma unroll
    for (int r = 0; r < 16; ++r) {
      int idx = tid + 256*r;
      int tl = idx & 63, ul = idx >> 6;
      int u = (uh0 + ul) >> 2;
      float x = (float)v_t[((size_t)(b*UHN + uh0 + ul))*TSEQ + ((t0 + tl + dly[u]) & (TSEQ-1))]
                * wg[u];
      Af[tl*OPITCH + ul] = (f16)x;
    }
#pragma unroll
    for (int r = 0; r < 2; ++r) {
      int idx = tid + 256*r;
      int fl = idx >> 3, seg = (idx & 7) << 3;
      const f16* src = &wo_t[(size_t)(f0 + fl)*UHN + uh0 + seg];
      *(f16x4*)&Bf[fl*OPITCH + seg]     = *(const f16x4*)(src);
      *(f16x4*)&Bf[fl*OPITCH + seg + 4] = *(const f16x4*)(src + 4);
    }
    __syncthreads();
#pragma unroll
    for (int ks = 0; ks < 2; ++ks) {
      const int kb = ks*32 + 4*g;
      f16x8 av[2], bv[2];
#pragma unroll
      for (int mf = 0; mf < 2; ++mf)
        av[mf] = ld_frag(&Af[(wm*32 + mf*16 + ln15)*OPITCH + kb]);
#pragma unroll
      for (int nf = 0; nf < 2; ++nf)
        bv[nf] = ld_frag(&Bf[(wn*32 + nf*16 + ln15)*OPITCH + kb]);
#pragma unroll
      for (int mf = 0; mf < 2; ++mf)
#pragma unroll
        for (int nf = 0; nf < 2; ++nf)
          acc[mf][nf] = __builtin_amdgcn_mfma_f32_16x16x32_f16(av[mf], bv[nf], acc[mf][nf], 0, 0, 0);
    }
  }

#pragma unroll
  for (int mf = 0; mf < 2; ++mf)
#pragma unroll
    for (int r = 0; r < 4; ++r) {
      int bt = t0g + wm*32 + mf*16 + g*4 + r;
#pragma unroll
      for (int nf = 0; nf < 2; ++nf) {
        int f = f0 + wn*32 + nf*16 + ln15;
        out[(size_t)bt*EE + f] = acc[mf][nf][r] + bo[f];
      }
    }
}

// ---------------------------------------------------------------------------
extern "C" void kernel_launch(void* const* d_in, const int* in_sizes, int n_in,
                              void* d_out, int out_size, void* d_ws, size_t ws_size,
                              hipStream_t stream) {
  (void)in_sizes; (void)n_in; (void)out_size; (void)ws_size;
  const float* hs = (const float*)d_in[0];
  const float* wq = (const float*)d_in[1];
  const float* bq = (const float*)d_in[2];
  const float* wk = (const float*)d_in[3];
  const float* bk = (const float*)d_in[4];
  const float* wv = (const float*)d_in[5];
  const float* bv = (const float*)d_in[6];
  const float* wo = (const float*)d_in[7];
  const float* bo = (const float*)d_in[8];
  float* out = (float*)d_out;

  // ws layout (bytes): q_t f32 | k_t f32 | v_t f16 | hs_h | hs_l | Wt_h | Wt_l
  //                    | wo_t | delay | wgt   ~= 93.2 MB
  char* p = (char*)d_ws;
  float* q_t  = (float*)p;  p += (size_t)BB*UHN*TSEQ*4;   // 33.55 MB
  float* k_t  = (float*)p;  p += (size_t)BB*UHN*TSEQ*4;
  f16*   v_t  = (f16*)p;    p += (size_t)BB*UHN*TSEQ*2;   // 16.78 MB
  f16*   hs_h = (f16*)p;    p += (size_t)BT*EE*2;         // 4.19 MB
  f16*   hs_l = (f16*)p;    p += (size_t)BT*EE*2;
  f16*   Wt_h = (f16*)p;    p += (size_t)3*UHN*EE*2;      // 0.39 MB
  f16*   Wt_l = (f16*)p;    p += (size_t)3*UHN*EE*2;
  f16*   wo_t = (f16*)p;    p += (size_t)EE*UHN*2;        // 0.13 MB
  int*   delay = (int*)p;   p += BB*EE*4;
  float* wgt   = (float*)p;

  prep_kernel<<<dim3(1088), 256, 0, stream>>>(hs, wq, wk, wv, wo,
                                              hs_h, hs_l, Wt_h, Wt_l, wo_t);
  proj_mfma<<<dim3(4, 128, 3), 256, 0, stream>>>(hs_h, hs_l, Wt_h, Wt_l,
                                                 bq, bk, bv, q_t, k_t, v_t);
  fftcorr_topk<<<dim3(1024), 256, 0, stream>>>(q_t, k_t, delay, wgt);
  out_mfma<<<dim3(256, 2), 256, 0, stream>>>(v_t, delay, wgt, wo_t, bo, out);
}